// Round 14
// baseline (102.493 us; speedup 1.0000x reference)
//
#include <hip/hip_runtime.h>
#include <hip/hip_bf16.h>
#include <math.h>

#define Bn 8
#define Ln 512
#define Dn 768
#define NHn 12
#define DHn 64
#define K1n 20
#define K2n 20
#define BST 72    // LDS B-tile row stride in shorts
#define TROWS 64  // B-tile rows per stage

// workspace layout (bytes) -- NO memset: acc/g_score zeroed by prep block 0,
// loc_part is fully written non-atomically by pairB (no init needed).
#define WS_ACC    0          // double acc[8]; bytes 48..51 = done-counter
#define WS_GSCORE 64         // float g_score[8*512] (16 KB)
#define WS_GTOP   16448      // int g_top[8*20]
#define WS_LOCP   17152      // float loc_part[12][8][20][512] (3.93 MB)
#define WS_SBF    3949312    // ushort sbf[8*12*512*64] bf16 head-major
#define WS_TBF    10240768   // ushort tbf[...] (ends 16532224)

typedef __attribute__((ext_vector_type(8))) short bf16x8;
typedef __attribute__((ext_vector_type(4))) float f32x4;

__device__ inline unsigned short f2bf(float x) {
  __hip_bfloat16 h = __float2bfloat16(x);
  return *reinterpret_cast<unsigned short*>(&h);
}
__device__ inline float bf2f(unsigned short u) {
  return __uint_as_float(((unsigned int)u) << 16);
}

// ---------------------------------------------------------------------------
// Prep: fp32 [b][row][h*64+k] -> bf16 head-major [b][h][row][k].
// Block 0 zeroes acc + g_score.
// ---------------------------------------------------------------------------
__global__ __launch_bounds__(256) void prep_bf16_kernel(
    const float* __restrict__ s, const float* __restrict__ t,
    unsigned short* __restrict__ sbf, unsigned short* __restrict__ tbf,
    float* __restrict__ g_score, int* __restrict__ accw) {
  int tid = threadIdx.x;
  if (blockIdx.x == 0) {
    if (tid < 16) accw[tid] = 0;                       // acc[0..7] + done
    for (int i = tid; i < Bn * Ln; i += 256) g_score[i] = 0.0f;
  }
  int gid = blockIdx.x * 256 + tid;
  int f = gid * 4;
  int col = f % Dn;
  int rb = f / Dn;
  int row = rb & (Ln - 1);
  int b = rb >> 9;
  int h = col >> 6;
  int k = col & 63;
  size_t dst = (((size_t)(b * NHn + h) * Ln + row) * DHn + k);
  float4 vs = *(const float4*)(s + f);
  float4 vt = *(const float4*)(t + f);
  ushort4 us, ut;
  us.x = f2bf(vs.x); us.y = f2bf(vs.y); us.z = f2bf(vs.z); us.w = f2bf(vs.w);
  ut.x = f2bf(vt.x); ut.y = f2bf(vt.y); ut.z = f2bf(vt.z); ut.w = f2bf(vt.w);
  *(ushort4*)(sbf + dst) = us;
  *(ushort4*)(tbf + dst) = ut;
}

// ---------------------------------------------------------------------------
// Kernel A v4 (unchanged from rounds 11-13): software-pipelined LDS staging.
// ---------------------------------------------------------------------------
__global__ __launch_bounds__(256) void pairA_kernel(
    const unsigned short* __restrict__ sbf, const unsigned short* __restrict__ tbf,
    const float* __restrict__ mask, float* __restrict__ g_score,
    double* __restrict__ acc) {
  const int b = blockIdx.x & 7;
  const int r = blockIdx.x >> 3;          // 0..95
  const int it = r / NHn;                 // 0..7
  const int h = r - it * NHn;             // 0..11
  const int tid = threadIdx.x;
  const int w = tid >> 6;                 // wave: rows [it*64 + w*16, +16)
  const int lane = tid & 63;
  const int lr = lane & 15, lg = lane >> 4;

  __shared__ unsigned short Bs[2][TROWS * BST];
  __shared__ unsigned short Bt[2][TROWS * BST];
  __shared__ float Mcol[Ln];
  __shared__ float gcol[Ln];
  __shared__ float wred[4];

  const int s_r0 = tid >> 3;              // 0..31
  const int s_r1 = s_r0 + 32;             // 32..63
  const int s_c = (tid & 7) * 8;

  for (int j = tid; j < Ln; j += 256) {
    Mcol[j] = mask[b * Ln + j];
    gcol[j] = 0.0f;
  }

  const size_t hb = (size_t)(b * NHn + h) * Ln;
  const int rw = it * 64 + w * 16;
  const unsigned short* pas = sbf + (hb + rw + lr) * DHn + lg * 8;
  const unsigned short* pat = tbf + (hb + rw + lr) * DHn + lg * 8;
  bf16x8 sa0 = *(const bf16x8*)pas;
  bf16x8 sa1 = *(const bf16x8*)(pas + 32);
  bf16x8 ta0 = *(const bf16x8*)pat;
  bf16x8 ta1 = *(const bf16x8*)(pat + 32);

  {
    bf16x8 v0 = *(const bf16x8*)(sbf + (hb + s_r0) * DHn + s_c);
    bf16x8 v1 = *(const bf16x8*)(sbf + (hb + s_r1) * DHn + s_c);
    bf16x8 u0 = *(const bf16x8*)(tbf + (hb + s_r0) * DHn + s_c);
    bf16x8 u1 = *(const bf16x8*)(tbf + (hb + s_r1) * DHn + s_c);
    *(bf16x8*)&Bs[0][s_r0 * BST + s_c] = v0;
    *(bf16x8*)&Bs[0][s_r1 * BST + s_c] = v1;
    *(bf16x8*)&Bt[0][s_r0 * BST + s_c] = u0;
    *(bf16x8*)&Bt[0][s_r1 * BST + s_c] = u1;
  }
  __syncthreads();

  float mrow[4];
  #pragma unroll
  for (int q = 0; q < 4; ++q) mrow[q] = Mcol[rw + lg * 4 + q];

  const f32x4 zero4 = {0.0f, 0.0f, 0.0f, 0.0f};
  float lpair = 0.0f;
  float rsum[4] = {0.0f, 0.0f, 0.0f, 0.0f};

  // ---- pass 1: diff^2 + row sums (pipelined over 8 tiles) ----
  #pragma unroll 1
  for (int t = 0; t < 8; ++t) {
    const int cur = t & 1;
    bf16x8 v0, v1, u0, u1;
    if (t < 7) {
      const int jn = (t + 1) * TROWS;
      v0 = *(const bf16x8*)(sbf + (hb + jn + s_r0) * DHn + s_c);
      v1 = *(const bf16x8*)(sbf + (hb + jn + s_r1) * DHn + s_c);
      u0 = *(const bf16x8*)(tbf + (hb + jn + s_r0) * DHn + s_c);
      u1 = *(const bf16x8*)(tbf + (hb + jn + s_r1) * DHn + s_c);
    }
    #pragma unroll
    for (int c = 0; c < 4; ++c) {
      const int jl = c * 16;
      const int j0 = t * TROWS + jl;
      const unsigned short* pbs = &Bs[cur][(jl + lr) * BST + lg * 8];
      const unsigned short* pbt = &Bt[cur][(jl + lr) * BST + lg * 8];
      bf16x8 sb0 = *(const bf16x8*)pbs;
      bf16x8 sb1 = *(const bf16x8*)(pbs + 32);
      bf16x8 tb0 = *(const bf16x8*)pbt;
      bf16x8 tb1 = *(const bf16x8*)(pbt + 32);
      f32x4 sacc = __builtin_amdgcn_mfma_f32_16x16x32_bf16(sa0, sb0, zero4, 0, 0, 0);
      sacc = __builtin_amdgcn_mfma_f32_16x16x32_bf16(sa1, sb1, sacc, 0, 0, 0);
      f32x4 tacc = __builtin_amdgcn_mfma_f32_16x16x32_bf16(ta0, tb0, zero4, 0, 0, 0);
      tacc = __builtin_amdgcn_mfma_f32_16x16x32_bf16(ta1, tb1, tacc, 0, 0, 0);
      const float mj = Mcol[j0 + lr];
      #pragma unroll
      for (int q = 0; q < 4; ++q) {
        const float mm = mrow[q] * mj;
        const float ss = sacc[q] * 0.125f * mm;
        const float st = tacc[q] * 0.125f * mm;
        const float d = ss - st;
        lpair += d * d;
        rsum[q] += __expf(st + (1.0f - mm) * (-10000.0f));
      }
    }
    if (t < 7) {
      const int nxt = cur ^ 1;
      *(bf16x8*)&Bs[nxt][s_r0 * BST + s_c] = v0;
      *(bf16x8*)&Bs[nxt][s_r1 * BST + s_c] = v1;
      *(bf16x8*)&Bt[nxt][s_r0 * BST + s_c] = u0;
      *(bf16x8*)&Bt[nxt][s_r1 * BST + s_c] = u1;
    }
    __syncthreads();
  }

  #pragma unroll
  for (int o = 1; o < 16; o <<= 1) {
    #pragma unroll
    for (int q = 0; q < 4; ++q) rsum[q] += __shfl_xor(rsum[q], o, 64);
  }
  float rscale[4];
  #pragma unroll
  for (int q = 0; q < 4; ++q)
    rscale[q] = mrow[q] / fmaxf(rsum[q], 1e-30f);

  // ---- pass 2: recompute e (t only), scale, column sums (pipelined) ----
  {
    bf16x8 u0 = *(const bf16x8*)(tbf + (hb + s_r0) * DHn + s_c);
    bf16x8 u1 = *(const bf16x8*)(tbf + (hb + s_r1) * DHn + s_c);
    *(bf16x8*)&Bt[0][s_r0 * BST + s_c] = u0;
    *(bf16x8*)&Bt[0][s_r1 * BST + s_c] = u1;
  }
  __syncthreads();

  #pragma unroll 1
  for (int t = 0; t < 8; ++t) {
    const int cur = t & 1;
    bf16x8 u0, u1;
    if (t < 7) {
      const int jn = (t + 1) * TROWS;
      u0 = *(const bf16x8*)(tbf + (hb + jn + s_r0) * DHn + s_c);
      u1 = *(const bf16x8*)(tbf + (hb + jn + s_r1) * DHn + s_c);
    }
    #pragma unroll
    for (int c = 0; c < 4; ++c) {
      const int jl = c * 16;
      const int j0 = t * TROWS + jl;
      const unsigned short* pbt = &Bt[cur][(jl + lr) * BST + lg * 8];
      bf16x8 tb0 = *(const bf16x8*)pbt;
      bf16x8 tb1 = *(const bf16x8*)(pbt + 32);
      f32x4 tacc = __builtin_amdgcn_mfma_f32_16x16x32_bf16(ta0, tb0, zero4, 0, 0, 0);
      tacc = __builtin_amdgcn_mfma_f32_16x16x32_bf16(ta1, tb1, tacc, 0, 0, 0);
      const float mj = Mcol[j0 + lr];
      float pc = 0.0f;
      #pragma unroll
      for (int q = 0; q < 4; ++q) {
        const float mm = mrow[q] * mj;
        const float st = tacc[q] * 0.125f * mm;
        const float e = __expf(st + (1.0f - mm) * (-10000.0f));
        pc += e * rscale[q];
      }
      pc += __shfl_xor(pc, 16, 64);
      pc += __shfl_xor(pc, 32, 64);
      if (lg == 0) atomicAdd(&gcol[j0 + lr], pc);
    }
    if (t < 7) {
      const int nxt = cur ^ 1;
      *(bf16x8*)&Bt[nxt][s_r0 * BST + s_c] = u0;
      *(bf16x8*)&Bt[nxt][s_r1 * BST + s_c] = u1;
    }
    __syncthreads();
  }

  #pragma unroll
  for (int o = 1; o < 64; o <<= 1) lpair += __shfl_xor(lpair, o, 64);
  if (lane == 0) wred[w] = lpair;
  __syncthreads();

  if (tid == 0) {
    atomicAdd(&acc[0], (double)((wred[0] + wred[1]) + (wred[2] + wred[3])));
  }
  {
    const int j0 = tid, j1 = tid + 256;
    atomicAdd(&g_score[b * Ln + j0], gcol[j0] * Mcol[j0]);
    atomicAdd(&g_score[b * Ln + j1], gcol[j1] * Mcol[j1]);
  }
}

// ---------------------------------------------------------------------------
// Kernel B (+ inline topk_g): one block per (b, h) = 96 blocks. Writes its
// own loc_part[h] slice NON-atomically.
// ---------------------------------------------------------------------------
__global__ __launch_bounds__(256, 4) void pairB_kernel(
    const unsigned short* __restrict__ tbf, const float* __restrict__ mask,
    const float* __restrict__ g_score, int* __restrict__ g_top,
    float* __restrict__ loc_part) {
  const int b = blockIdx.x & 7;
  const int h = blockIdx.x >> 3;
  const int tid = threadIdx.x;
  const int w = tid >> 6, lane = tid & 63;
  const int lr = lane & 15, lg = lane >> 4;
  const int cw = w * 128;

  __shared__ int gidx[32];
  __shared__ float mrow_s[32];
  __shared__ float rscale_s[32];
  __shared__ float redsum[4][32];
  __shared__ float McolB[Ln];
  __shared__ unsigned short es[32][Ln + 8];

  for (int j = tid; j < Ln; j += 256) McolB[j] = mask[b * Ln + j];
  if (w == 1 && lane < 32 - K1n) gidx[K1n + lane] = 0;
  if (w == 0) {
    float v[8];
    #pragma unroll
    for (int q = 0; q < 8; ++q) v[q] = g_score[b * Ln + q * 64 + lane];
    for (int r = 0; r < K1n; ++r) {
      float bv = v[0]; int bq = 0;
      #pragma unroll
      for (int q = 1; q < 8; ++q) if (v[q] > bv) { bv = v[q]; bq = q; }
      int bj = bq * 64 + lane;
      #pragma unroll
      for (int o = 1; o < 64; o <<= 1) {
        float ov = __shfl_xor(bv, o, 64);
        int oj = __shfl_xor(bj, o, 64);
        if (ov > bv || (ov == bv && oj < bj)) { bv = ov; bj = oj; }
      }
      if (lane == 0) {
        gidx[r] = bj;
        if (h == 0) g_top[b * K1n + r] = bj;
      }
      const int wq = bj >> 6, wl = bj & 63;
      #pragma unroll
      for (int q = 0; q < 8; ++q)
        if (q == wq && lane == wl) v[q] = -3.0e38f;
    }
  }
  __syncthreads();
  if (tid < 32) mrow_s[tid] = (tid < K1n) ? McolB[gidx[tid]] : 0.0f;
  __syncthreads();

  const size_t hb = (size_t)(b * NHn + h) * Ln;
  bf16x8 ta[2][2];
  #pragma unroll
  for (int rt = 0; rt < 2; ++rt) {
    const unsigned short* p = tbf + (hb + gidx[rt * 16 + lr]) * DHn + lg * 8;
    ta[rt][0] = *(const bf16x8*)p;
    ta[rt][1] = *(const bf16x8*)(p + 32);
  }
  const f32x4 zero4 = {0.0f, 0.0f, 0.0f, 0.0f};
  float rsum[2][4] = {{0, 0, 0, 0}, {0, 0, 0, 0}};
  #pragma unroll 1
  for (int ct = 0; ct < 8; ++ct) {
    const int j0 = cw + ct * 16;
    const unsigned short* pb = tbf + (hb + j0 + lr) * DHn + lg * 8;
    bf16x8 tb0 = *(const bf16x8*)pb;
    bf16x8 tb1 = *(const bf16x8*)(pb + 32);
    const float mj = McolB[j0 + lr];
    #pragma unroll
    for (int rt = 0; rt < 2; ++rt) {
      f32x4 tacc = __builtin_amdgcn_mfma_f32_16x16x32_bf16(ta[rt][0], tb0, zero4, 0, 0, 0);
      tacc = __builtin_amdgcn_mfma_f32_16x16x32_bf16(ta[rt][1], tb1, tacc, 0, 0, 0);
      #pragma unroll
      for (int q = 0; q < 4; ++q) {
        const int ri = rt * 16 + lg * 4 + q;
        const float mm = mrow_s[ri] * mj;
        const float st = tacc[q] * 0.125f * mm;
        const float e = __expf(st + (1.0f - mm) * (-10000.0f));
        rsum[rt][q] += e;
        es[ri][j0 + lr] = f2bf(e);
      }
    }
  }
  #pragma unroll
  for (int o = 1; o < 16; o <<= 1) {
    #pragma unroll
    for (int rt = 0; rt < 2; ++rt)
      #pragma unroll
      for (int q = 0; q < 4; ++q) rsum[rt][q] += __shfl_xor(rsum[rt][q], o, 64);
  }
  if (lr == 0) {
    #pragma unroll
    for (int rt = 0; rt < 2; ++rt)
      #pragma unroll
      for (int q = 0; q < 4; ++q) redsum[w][rt * 16 + lg * 4 + q] = rsum[rt][q];
  }
  __syncthreads();
  if (tid < 32) {
    const float fs = redsum[0][tid] + redsum[1][tid] + redsum[2][tid] + redsum[3][tid];
    rscale_s[tid] = mrow_s[tid] / fmaxf(fs, 1e-30f);
  }
  __syncthreads();
  float* lp = loc_part + (size_t)(h * Bn + b) * K1n * Ln;
  for (int idx = tid; idx < K1n * Ln; idx += 256) {
    const int ri = idx >> 9, j = idx & (Ln - 1);
    const float e = bf2f(es[ri][j]);
    lp[idx] = e * rscale_s[ri] * McolB[j];     // non-atomic, full coverage
  }
}

// ---------------------------------------------------------------------------
// Triplet v3: burst-load. Round 13 PMC: 43 us at 280 GB/s effective -- HBM
// latency-bound, ~6 loads in flight per wave (rolled j-loop serialized by
// per-iteration reduce). Now phase 2a is a FULLY-UNROLLED flat task map
// (120 chunk-tasks over 8 waves, 15 static iters each) so the compiler
// hoists all 15 independent float4 loads -> ~10x the MLP. Diffs stored
// unnormalized bf16; norms from fp32 partials in statically-indexed regs;
// normalize in place (2b) before the MFMA Gram.
// ---------------------------------------------------------------------------
#define TPW (Dn + 16)

__global__ __launch_bounds__(512, 1) void triplet_kernel(
    const float* __restrict__ s_rep, const float* __restrict__ t_rep,
    const float* __restrict__ mask, const int* __restrict__ g_top,
    const float* __restrict__ loc_part, double* __restrict__ acc,
    unsigned int* __restrict__ done_cnt, float* __restrict__ out) {
  const int blk = blockIdx.x, tid = threadIdx.x;
  const int b = blk / K1n, i1 = blk % K1n;
  const int w = tid >> 6, lane = tid & 63;
  const int lr = lane & 15, lg = lane >> 4;

  __shared__ unsigned short NS[32][TPW];
  __shared__ unsigned short NT[32][TPW];
  __shared__ float locsum[Ln];
  __shared__ float gsr[Dn], gtr[Dn];
  __shared__ float G[2][K2n][K2n + 1];
  __shared__ float ssqL[40];
  __shared__ float rsinv[40];
  __shared__ int lidx[K2n];
  __shared__ float fl2[K2n];
  __shared__ float sred[8], cred[8];
  __shared__ int is_last;
  __shared__ float red[8];

  const int g = g_top[b * K1n + i1];

  // phase 0: parallel 12-partial column sums + g-row staging
  {
    const int j = tid;
    float sv = 0.0f;
    #pragma unroll
    for (int hh = 0; hh < NHn; ++hh)
      sv += loc_part[((size_t)(hh * Bn + b) * K1n + i1) * Ln + j];
    locsum[j] = (j == g) ? 0.0f : sv;
  }
  {
    const float* pgs = s_rep + (size_t)(b * Ln + g) * Dn;
    const float* pgt = t_rep + (size_t)(b * Ln + g) * Dn;
    if (tid < 192) {
      *(float4*)&gsr[tid * 4] = *(const float4*)&pgs[tid * 4];
    } else if (tid < 384) {
      const int q4 = tid - 192;
      *(float4*)&gtr[q4 * 4] = *(const float4*)&pgt[q4 * 4];
    }
  }
  __syncthreads();

  // phase 1: wave-0 register top-k over LDS locsum (tie -> lowest index)
  if (w == 0) {
    float v[8];
    #pragma unroll
    for (int q = 0; q < 8; ++q) v[q] = locsum[q * 64 + lane];
    for (int r = 0; r < K2n; ++r) {
      float bv = v[0]; int bq = 0;
      #pragma unroll
      for (int q = 1; q < 8; ++q) if (v[q] > bv) { bv = v[q]; bq = q; }
      int bj = bq * 64 + lane;
      #pragma unroll
      for (int o = 1; o < 64; o <<= 1) {
        float ov = __shfl_xor(bv, o, 64);
        int oj = __shfl_xor(bj, o, 64);
        if (ov > bv || (ov == bv && oj < bj)) { bv = ov; bj = oj; }
      }
      if (lane == 0) lidx[r] = bj;
      const int wq = bj >> 6, wl = bj & 63;
      #pragma unroll
      for (int q = 0; q < 8; ++q)
        if (q == wq && lane == wl) v[q] = -3.0e38f;
    }
  }
  __syncthreads();
  if (tid < K2n)
    fl2[tid] = (mask[b * Ln + g] + mask[b * Ln + lidx[tid]] == 2.0f) ? 1.0f : 0.0f;

  // phase 2a: burst diff load. 120 tasks = 40 rowtensors x 3 chunks; wave w
  // owns rowtensors w*5..w*5+4 (15 fully-unrolled iters -> loads hoisted).
  {
    float ssq_acc[5] = {0.0f, 0.0f, 0.0f, 0.0f, 0.0f};
    #pragma unroll
    for (int i = 0; i < 15; ++i) {
      const int rl = i / 3;                  // 0..4 (static)
      const int q = i % 3;                   // chunk (static)
      const int rt = w * 5 + rl;             // rowtensor 0..39
      const bool isS = rt < 20;
      const int row = isS ? rt : rt - 20;
      const int c = q * 256 + lane * 4;
      const float* src = (isS ? s_rep : t_rep) +
                         (size_t)(b * Ln + lidx[row]) * Dn + c;
      float4 x = *(const float4*)src;
      const float* gp = isS ? gsr : gtr;
      float4 a = *(const float4*)&gp[c];
      float4 d = make_float4(a.x - x.x, a.y - x.y, a.z - x.z, a.w - x.w);
      ushort4 u;
      u.x = f2bf(d.x); u.y = f2bf(d.y); u.z = f2bf(d.z); u.w = f2bf(d.w);
      if (isS) *(ushort4*)&NS[row][c] = u;
      else     *(ushort4*)&NT[row][c] = u;
      ssq_acc[rl] += d.x * d.x + d.y * d.y + d.z * d.z + d.w * d.w;
    }
    #pragma unroll
    for (int rl = 0; rl < 5; ++rl) {
      float v = ssq_acc[rl];
      #pragma unroll
      for (int o = 1; o < 64; o <<= 1) v += __shfl_xor(v, o, 64);
      if (lane == 0) ssqL[w * 5 + rl] = v;
    }
  }
  __syncthreads();
  if (tid < 40) rsinv[tid] = 1.0f / fmaxf(sqrtf(ssqL[tid]), 1e-12f);
  __syncthreads();

  // phase 2b: normalize bf16 diffs in place
  for (int idx = tid; idx < 40 * 192; idx += 512) {
    const int rt = idx / 192;
    const int c = (idx - rt * 192) * 4;
    const float sc = rsinv[rt];
    unsigned short* N = (rt < 20) ? &NS[rt][c] : &NT[rt - 20][c];
    ushort4 u = *(ushort4*)N;
    u.x = f2bf(bf2f(u.x) * sc); u.y = f2bf(bf2f(u.y) * sc);
    u.z = f2bf(bf2f(u.z) * sc); u.w = f2bf(bf2f(u.w) * sc);
    *(ushort4*)N = u;
  }
  __syncthreads();

  // phase 3: Gram as 8 wave-tasks: tensor = w&1, quadrant = w>>1
  {
    const int ts = w & 1;
    const int qr = w >> 2;
    const int qc = (w >> 1) & 1;
    const unsigned short (*N)[TPW] = ts ? NT : NS;
    f32x4 acc4 = {0.0f, 0.0f, 0.0f, 0.0f};
    #pragma unroll
    for (int ks = 0; ks < 24; ++ks) {
      const int kk = ks * 32 + lg * 8;
      bf16x8 a8 = *(const bf16x8*)&N[qr * 16 + lr][kk];
      bf16x8 b8 = *(const bf16x8*)&N[qc * 16 + lr][kk];
      acc4 = __builtin_amdgcn_mfma_f32_16x16x32_bf16(a8, b8, acc4, 0, 0, 0);
    }
    #pragma unroll
    for (int q = 0; q < 4; ++q) {
      const int j2 = qr * 16 + lg * 4 + q;
      const int k2 = qc * 16 + lr;
      if (j2 < K2n && k2 < K2n) G[ts][j2][k2] = acc4[q];
    }
  }
  __syncthreads();

  // phase 4: huber + masks on 400 pairs
  float psum = 0.0f, pcnt = 0.0f;
  if (tid < K2n * K2n) {
    const int j2 = tid / K2n, k2 = tid - j2 * K2n;
    if (j2 != k2) {
      const float am = fl2[j2] * fl2[k2];
      const float sv0 = G[0][j2][k2];
      const float tv0 = G[1][j2][k2];
      const bool smv = (am != 0.0f) && (sv0 != 0.0f);
      const bool tmv = (am != 0.0f) && (tv0 != 0.0f);
      const float sv = smv ? sv0 : 0.0f;
      const float tv = tmv ? tv0 : 0.0f;
      const float d = sv - tv;
      const float ad = fabsf(d);
      psum = (ad < 1.0f) ? 0.5f * d * d : (ad - 0.5f);
      pcnt = smv ? 1.0f : 0.0f;
    }
  }
  #pragma unroll
  for (int o = 1; o < 64; o <<= 1) {
    psum += __shfl_xor(psum, o, 64);
    pcnt += __shfl_xor(pcnt, o, 64);
  }
  if (lane == 0) { sred[w] = psum; cred[w] = pcnt; }
  __syncthreads();
  if (tid == 0) {
    float ps = 0.0f, pcs = 0.0f;
    #pragma unroll
    for (int i = 0; i < 8; ++i) { ps += sred[i]; pcs += cred[i]; }
    atomicAdd(&acc[1], (double)ps);
    atomicAdd(&acc[2], (double)pcs);
    __threadfence();
    const unsigned int done = atomicAdd(done_cnt, 1u);
    is_last = (done == (unsigned int)(Bn * K1n - 1)) ? 1 : 0;
  }
  __syncthreads();

  if (is_last) {
    double sm = 0.0;
    for (int bb = 0; bb < Bn; ++bb) {
      float p = (tid < Ln) ? mask[bb * Ln + tid] : 0.0f;
      #pragma unroll
      for (int o = 1; o < 64; o <<= 1) p += __shfl_xor(p, o, 64);
      __syncthreads();
      if ((tid & 63) == 0) red[tid >> 6] = p;
      __syncthreads();
      if (tid == 0) {
        float rs = 0.0f;
        #pragma unroll
        for (int i = 0; i < 8; ++i) rs += red[i];
        sm += (double)rs * (double)rs;
      }
    }
    __syncthreads();
    if (tid == 0) {
      const double a0 = atomicAdd(&acc[0], 0.0);
      const double a1 = atomicAdd(&acc[1], 0.0);
      const double a2 = atomicAdd(&acc[2], 0.0);
      const double lp = a0 / ((double)NHn * sm);
      const double lt = a1 / a2;
      out[0] = (float)(lp + lt);
    }
  }
}

// ---------------------------------------------------------------------------
extern "C" void kernel_launch(void* const* d_in, const int* in_sizes, int n_in,
                              void* d_out, int out_size, void* d_ws, size_t ws_size,
                              hipStream_t stream) {
  const float* s_rep = (const float*)d_in[0];
  const float* t_rep = (const float*)d_in[1];
  const float* mask  = (const float*)d_in[2];
  float* out = (float*)d_out;

  char* w = (char*)d_ws;
  double* acc      = (double*)(w + WS_ACC);
  unsigned int* done_cnt = (unsigned int*)(w + WS_ACC + 48);
  float* g_score   = (float*)(w + WS_GSCORE);
  int* g_top       = (int*)(w + WS_GTOP);
  float* loc_part  = (float*)(w + WS_LOCP);
  unsigned short* sbf = (unsigned short*)(w + WS_SBF);
  unsigned short* tbf = (unsigned short*)(w + WS_TBF);

  prep_bf16_kernel<<<Bn * Ln * Dn / 4 / 256, 256, 0, stream>>>(
      s_rep, t_rep, sbf, tbf, g_score, (int*)(w + WS_ACC));
  pairA_kernel<<<Bn * NHn * (Ln / 64), 256, 0, stream>>>(sbf, tbf, mask, g_score, acc);
  pairB_kernel<<<Bn * NHn, 256, 0, stream>>>(tbf, mask, g_score, g_top, loc_part);
  triplet_kernel<<<Bn * K1n, 512, 0, stream>>>(s_rep, t_rep, mask, g_top, loc_part,
                                               acc, done_cnt, out);
}